// Round 1
// 9773.629 us; speedup vs baseline: 1.2934x; 1.2934x over previous
//
#include <hip/hip_runtime.h>

#define TSEQ 2048
#define DM   1024
#define NBLK 4
#define NHEAD 16
#define HDIM 64
#define DFF  4096
#define NVOC 32000

typedef unsigned short u16;
typedef __attribute__((ext_vector_type(8))) short short8;
typedef __attribute__((ext_vector_type(4))) float f32x4;

// ---------------- device-global scratch ----------------
// f32 activations
__device__ float g_h[TSEQ * DM];
__device__ float g_q[TSEQ * DM];
__device__ float g_k[TSEQ * DM];
__device__ float g_v[TSEQ * DM];
// bf16 hi/lo split activations (A operands)
__device__ u16 g_xnh[TSEQ * DM];
__device__ u16 g_xnl[TSEQ * DM];
__device__ u16 g_ffh[TSEQ * DFF];
__device__ u16 g_ffl[TSEQ * DFF];
// bf16 hi/lo split transposed weights, layout [N][K] row-major
__device__ u16 g_wqkvh[NBLK * 3 * DM * DM];
__device__ u16 g_wqkvl[NBLK * 3 * DM * DM];
__device__ u16 g_w1h[NBLK * DM * DFF];
__device__ u16 g_w1l[NBLK * DM * DFF];
__device__ u16 g_w2h[NBLK * DFF * DM];
__device__ u16 g_w2l[NBLK * DFF * DM];
__device__ u16 g_wvh[NVOC * DM];
__device__ u16 g_wvl[NVOC * DM];
__device__ float g_bqkv[NBLK * 3 * DM];

// ---------------- helpers ----------------
__device__ __forceinline__ u16 f2bf(float x) {           // RNE f32 -> bf16
  union { float f; unsigned u; } v; v.f = x;
  unsigned r = (v.u >> 16) & 1u;
  return (u16)((v.u + 0x7fffu + r) >> 16);
}
__device__ __forceinline__ float b2f(u16 h) {
  union { float f; unsigned u; } v; v.u = ((unsigned)h) << 16; return v.f;
}
// async global->LDS, 16B per lane; LDS dest = wave-uniform base + lane*16
__device__ __forceinline__ void load16(const u16* g, u16* l) {
  __builtin_amdgcn_global_load_lds(
      (const __attribute__((address_space(1))) unsigned int*)(const void*)g,
      (__attribute__((address_space(3))) unsigned int*)(void*)l, 16, 0, 0);
}

__device__ __forceinline__ const u16* wsel_h(int s) {
  switch (s) { case 0: return g_wqkvh; case 1: return g_w1h;
               case 2: return g_w2h;   default: return g_wvh; }
}
__device__ __forceinline__ const u16* wsel_l(int s) {
  switch (s) { case 0: return g_wqkvl; case 1: return g_w1l;
               case 2: return g_w2l;   default: return g_wvl; }
}

// ---------------- embedding ----------------
__global__ __launch_bounds__(256) void embed_kernel(const int* __restrict__ x,
                                                    const float* __restrict__ tok,
                                                    const float* __restrict__ pos) {
  int t = blockIdx.x;
  const float* trow = tok + (long)x[t] * DM;
  const float* prow = pos + (long)t * DM;
  float* hrow = g_h + (long)t * DM;
  for (int i = threadIdx.x; i < DM; i += 256)
    hrow[i] = trow[i] + prow[i];
}

// ---------------- layernorm: g_h -> (g_xnh, g_xnl) bf16 split ----------------
__global__ __launch_bounds__(256) void ln_kernel(const float* __restrict__ gamma,
                                                 const float* __restrict__ beta) {
  int t = blockIdx.x;
  const float* xr = g_h + (long)t * DM;
  float s = 0.f, ss = 0.f;
  for (int i = threadIdx.x; i < DM; i += 256) {
    float v = xr[i];
    s += v; ss += v * v;
  }
#pragma unroll
  for (int off = 32; off; off >>= 1) {
    s  += __shfl_down(s, off);
    ss += __shfl_down(ss, off);
  }
  __shared__ float red[2][4];
  int w = threadIdx.x >> 6;
  if ((threadIdx.x & 63) == 0) { red[0][w] = s; red[1][w] = ss; }
  __syncthreads();
  s  = red[0][0] + red[0][1] + red[0][2] + red[0][3];
  ss = red[1][0] + red[1][1] + red[1][2] + red[1][3];
  float mean = s * (1.f / DM);
  float var  = ss * (1.f / DM) - mean * mean;
  float rstd = rsqrtf(var + 1e-5f);
  for (int i = threadIdx.x; i < DM; i += 256) {
    float xv = (xr[i] - mean) * rstd * gamma[i] + beta[i];
    long o = (long)t * DM + i;
    u16 h = f2bf(xv);
    g_xnh[o] = h;
    g_xnl[o] = f2bf(xv - b2f(h));
  }
}

// ---------------- weight transpose + bf16 split ----------------
// src element (k,n) at src[(n>>6)*sH + k*sD + (n&63)]
// dst: [N][K] row-major bf16 hi/lo; grid = (N/64, K/64), 256 threads
__global__ __launch_bounds__(256) void wsplit_t(const float* __restrict__ src,
                                                int dsel, long doff,
                                                int K, long sD, long sH) {
  __shared__ float tile[64][65];
  u16* dh = const_cast<u16*>(wsel_h(dsel)) + doff;
  u16* dl = const_cast<u16*>(wsel_l(dsel)) + doff;
  int n0 = blockIdx.x * 64, k0 = blockIdx.y * 64;
  int tid = threadIdx.x, ln = tid & 63, sub = tid >> 6;
  const float* sbase = src + (long)(n0 >> 6) * sH + ln;
#pragma unroll
  for (int r = 0; r < 16; ++r) {
    int kk = sub * 16 + r;
    tile[kk][ln] = sbase[(long)(k0 + kk) * sD];
  }
  __syncthreads();
#pragma unroll
  for (int r = 0; r < 16; ++r) {
    int nn = sub * 16 + r;
    float v = tile[ln][nn];               // element (k0+ln, n0+nn)
    long o = (long)(n0 + nn) * K + k0 + ln;
    u16 h = f2bf(v);
    dh[o] = h;
    dl[o] = f2bf(v - b2f(h));
  }
}

// concat q/k/v biases per layer into g_bqkv[NBLK][3*DM]
__global__ __launch_bounds__(256) void bias_qkv(const float* __restrict__ bq,
                                                const float* __restrict__ bk,
                                                const float* __restrict__ bv) {
  int i = blockIdx.x * 256 + threadIdx.x;   // grid covers NBLK*3*DM exactly
  int l = i / (3 * DM);
  int j = i % (3 * DM);
  const float* s = (j < DM) ? bq : (j < 2 * DM) ? bk : bv;
  g_bqkv[i] = s[(long)l * DM + (j & (DM - 1))];
}

// ---------------- MFMA GEMM, bf16x3 split precision ----------------
// C[M,N] = A[M,K] @ W[K,N] (+bias, relu/resid/split per outmode)
// A given as hi/lo bf16 [M][K]; W given as hi/lo bf16 transposed [N][K].
// BN=128 fixed; BM template (128 or 64); BK=32; 256 threads = 4 waves.
// LDS fragment-order layout: tile mt/nt (16 rows) -> 64 lanes x 16B, matching
// mfma_f32_16x16x32_bf16 operand layout (lane&15 = row/col, lane>>4 = k/8).
// outmode: 0 = f32 -> Cout; 1 = bf16 split -> g_ffh/g_ffl;
//          2 = qkv scatter -> g_q/g_k/g_v; 3 = residual add -> g_h
template <int BM>
__global__ __launch_bounds__(256) void gemm_mfma(
    int aSel, int wSel, long woff,
    const float* __restrict__ biasPtr, long boff, float* __restrict__ Cout,
    int N, int K, int relu, int outmode) {
  constexpr int WR = BM / 64;            // wave rows: 2 (BM=128) or 1 (BM=64)
  constexpr int WC = 4 / WR;             // wave cols: 2 or 4
  constexpr int NR = 128 / (16 * WC);    // 16x16 tiles per wave in N: 4 or 2
  __shared__ __align__(16) u16 lA[2][BM * 32];
  __shared__ __align__(16) u16 lB[2][128 * 32];

  const u16* Ah = aSel ? g_ffh : g_xnh;
  const u16* Al = aSel ? g_ffl : g_xnl;
  const u16* Bh = wsel_h(wSel) + woff;
  const u16* Bl = wsel_l(wSel) + woff;
  const float* bias = biasPtr ? biasPtr : (g_bqkv + boff);

  const int tid = threadIdx.x;
  const int w = tid >> 6, lane = tid & 63;
  const int wr = w / WC, wc = w % WC;
  const int n0 = blockIdx.x * 128;
  const int m0 = blockIdx.y * BM;
  const int klane = (lane >> 4) * 8;

  long aoff[WR], boffv[2];
#pragma unroll
  for (int i = 0; i < WR; ++i)
    aoff[i] = (long)(m0 + (i * 4 + w) * 16 + (lane & 15)) * K + klane;
#pragma unroll
  for (int i = 0; i < 2; ++i)
    boffv[i] = (long)(n0 + (i * 4 + w) * 16 + (lane & 15)) * K + klane;

  const u16* pa0 = &lA[0][(wr * 4) * 512 + lane * 8];
  const u16* pa1 = &lA[1][(wr * 4) * 512 + lane * 8];
  const u16* pb0 = &lB[0][(wc * NR) * 512 + lane * 8];
  const u16* pb1 = &lB[1][(wc * NR) * 512 + lane * 8];

  f32x4 acc[4][NR] = {};

  for (int k0 = 0; k0 < K; k0 += 32) {
    // stage next K-slab: hi+lo of A and W, fragment-ordered, 16B/lane
#pragma unroll
    for (int i = 0; i < WR; ++i) {
      load16(Ah + aoff[i] + k0, &lA[0][(i * 4 + w) * 512]);
      load16(Al + aoff[i] + k0, &lA[1][(i * 4 + w) * 512]);
    }
#pragma unroll
    for (int i = 0; i < 2; ++i) {
      load16(Bh + boffv[i] + k0, &lB[0][(i * 4 + w) * 512]);
      load16(Bl + boffv[i] + k0, &lB[1][(i * 4 + w) * 512]);
    }
    __syncthreads();   // drains vmcnt -> staging visible to all waves

    short8 a[4][2], b[NR][2];
#pragma unroll
    for (int mi = 0; mi < 4; ++mi) {
      a[mi][0] = *(const short8*)(const void*)(pa0 + mi * 512);
      a[mi][1] = *(const short8*)(const void*)(pa1 + mi * 512);
    }
#pragma unroll
    for (int ni = 0; ni < NR; ++ni) {
      b[ni][0] = *(const short8*)(const void*)(pb0 + ni * 512);
      b[ni][1] = *(const short8*)(const void*)(pb1 + ni * 512);
    }
#pragma unroll
    for (int mi = 0; mi < 4; ++mi)
#pragma unroll
      for (int ni = 0; ni < NR; ++ni) {
        acc[mi][ni] = __builtin_amdgcn_mfma_f32_16x16x32_bf16(a[mi][0], b[ni][0], acc[mi][ni], 0, 0, 0);
        acc[mi][ni] = __builtin_amdgcn_mfma_f32_16x16x32_bf16(a[mi][0], b[ni][1], acc[mi][ni], 0, 0, 0);
        acc[mi][ni] = __builtin_amdgcn_mfma_f32_16x16x32_bf16(a[mi][1], b[ni][0], acc[mi][ni], 0, 0, 0);
      }
    __syncthreads();   // all reads done before next overwrite
  }

  // epilogue: C/D layout col = lane&15, row = (lane>>4)*4 + r
#pragma unroll
  for (int mi = 0; mi < 4; ++mi)
#pragma unroll
    for (int ni = 0; ni < NR; ++ni) {
      const int col = n0 + wc * (NR * 16) + ni * 16 + (lane & 15);
      const int row0 = m0 + wr * 64 + mi * 16 + ((lane >> 4) << 2);
      const float bv = bias[col];
#pragma unroll
      for (int r = 0; r < 4; ++r) {
        float v2 = acc[mi][ni][r] + bv;
        if (relu) v2 = fmaxf(v2, 0.f);
        const long row = row0 + r;
        if (outmode == 0) {
          Cout[row * (long)N + col] = v2;
        } else if (outmode == 1) {
          long o = row * (long)N + col;
          u16 h = f2bf(v2);
          g_ffh[o] = h;
          g_ffl[o] = f2bf(v2 - b2f(h));
        } else if (outmode == 2) {
          float* buf = (col < DM) ? g_q : (col < 2 * DM) ? g_k : g_v;
          buf[row * (long)DM + (col & (DM - 1))] = v2;
        } else {
          long o = row * (long)N + col;
          g_h[o] += v2;
        }
      }
    }
}

// ---------------- flash attention (f32, online softmax) — unchanged ----------------
__global__ __launch_bounds__(256) void attn_kernel() {
  __shared__ float kb[64 * 64];
  __shared__ float vb[64 * 64];
  __shared__ float qb[4][64];
  int head = blockIdx.y;
  int t0 = blockIdx.x * 4;
  int tid = threadIdx.x;
  int w = tid >> 6, lane = tid & 63;
  int t = t0 + w;
  qb[w][lane] = g_q[(long)t * DM + head * HDIM + lane];
  const float NEG = -1e30f;
  const float scale = 0.03125f;  // 1/sqrt(D) = 1/32
  float m_run = NEG, l_run = 0.f, o = 0.f;
  int smax = t0 + 3;
  for (int s0 = 0; s0 <= smax; s0 += 64) {
    __syncthreads();
#pragma unroll
    for (int i = 0; i < 16; ++i) {
      int e = tid + i * 256;
      int r = e >> 6, c = e & 63;
      int srow = s0 + r; if (srow > TSEQ - 1) srow = TSEQ - 1;
      kb[e] = g_k[(long)srow * DM + head * HDIM + c];
      vb[e] = g_v[(long)srow * DM + head * HDIM + c];
    }
    __syncthreads();
    int s = s0 + lane;
    float sc = NEG;
    if (s <= t) {
      float d = 0.f;
#pragma unroll
      for (int j = 0; j < 64; ++j) {
        int jj = (j + lane) & 63;           // rotate: kills 64-way LDS conflict
        d += qb[w][jj] * kb[lane * 64 + jj];
      }
      sc = d * scale;
    }
    float mx = sc;
#pragma unroll
    for (int off = 32; off; off >>= 1) mx = fmaxf(mx, __shfl_xor(mx, off));
    float m_new = fmaxf(m_run, mx);
    float p = __expf(sc - m_new);
    float alpha = __expf(m_run - m_new);
    float psum = p;
#pragma unroll
    for (int off = 32; off; off >>= 1) psum += __shfl_xor(psum, off);
    l_run = l_run * alpha + psum;
    m_run = m_new;
    o *= alpha;
#pragma unroll
    for (int s_i = 0; s_i < 64; ++s_i) {
      float ps = __shfl(p, s_i);
      o += ps * vb[s_i * 64 + lane];
    }
  }
  g_h[(long)t * DM + head * HDIM + lane] += o / l_run;
}

extern "C" void kernel_launch(void* const* d_in, const int* in_sizes, int n_in,
                              void* d_out, int out_size, void* d_ws, size_t ws_size,
                              hipStream_t stream) {
  (void)in_sizes; (void)n_in; (void)out_size; (void)d_ws; (void)ws_size;
  const int*   x    = (const int*)  d_in[0];
  const float* tok  = (const float*)d_in[1];
  const float* pos  = (const float*)d_in[2];
  const float* wq   = (const float*)d_in[3];
  const float* bq   = (const float*)d_in[4];
  const float* wk   = (const float*)d_in[5];
  const float* bk   = (const float*)d_in[6];
  const float* wv   = (const float*)d_in[7];
  const float* bv   = (const float*)d_in[8];
  const float* ln1g = (const float*)d_in[9];
  const float* ln1b = (const float*)d_in[10];
  const float* ln2g = (const float*)d_in[11];
  const float* ln2b = (const float*)d_in[12];
  const float* w1   = (const float*)d_in[13];
  const float* b1   = (const float*)d_in[14];
  const float* w2   = (const float*)d_in[15];
  const float* b2   = (const float*)d_in[16];
  const float* lnfg = (const float*)d_in[17];
  const float* lnfb = (const float*)d_in[18];
  const float* wvoc = (const float*)d_in[19];
  const float* bvoc = (const float*)d_in[20];
  float* out = (float*)d_out;

  // ---- weight conversion (transpose + bf16 hi/lo split), every launch ----
  for (int l = 0; l < NBLK; ++l) {
    long base = (long)l * 3 * DM * DM;
    wsplit_t<<<dim3(DM / 64, DM / 64), 256, 0, stream>>>(
        wq + (long)l * DM * DM, 0, base,                DM, HDIM, (long)DM * HDIM);
    wsplit_t<<<dim3(DM / 64, DM / 64), 256, 0, stream>>>(
        wk + (long)l * DM * DM, 0, base + (long)DM * DM, DM, HDIM, (long)DM * HDIM);
    wsplit_t<<<dim3(DM / 64, DM / 64), 256, 0, stream>>>(
        wv + (long)l * DM * DM, 0, base + 2L * DM * DM, DM, HDIM, (long)DM * HDIM);
    wsplit_t<<<dim3(DFF / 64, DM / 64), 256, 0, stream>>>(
        w1 + (long)l * DM * DFF, 1, (long)l * DM * DFF, DM, DFF, 64);
    wsplit_t<<<dim3(DM / 64, DFF / 64), 256, 0, stream>>>(
        w2 + (long)l * DFF * DM, 2, (long)l * DFF * DM, DFF, DM, 64);
  }
  wsplit_t<<<dim3(NVOC / 64, DM / 64), 256, 0, stream>>>(wvoc, 3, 0, DM, NVOC, 64);
  bias_qkv<<<NBLK * 3 * DM / 256, 256, 0, stream>>>(bq, bk, bv);

  // ---- forward pass ----
  embed_kernel<<<TSEQ, 256, 0, stream>>>(x, tok, pos);
  for (int l = 0; l < NBLK; ++l) {
    long base = (long)l * 3 * DM * DM;
    ln_kernel<<<TSEQ, 256, 0, stream>>>(ln1g + l * DM, ln1b + l * DM);
    // fused QKV: N = 3*DM, scatter into g_q/g_k/g_v
    gemm_mfma<64><<<dim3(3 * DM / 128, TSEQ / 64), 256, 0, stream>>>(
        0, 0, base, nullptr, (long)l * 3 * DM, nullptr, 3 * DM, DM, 0, 2);
    attn_kernel<<<dim3(TSEQ / 4, NHEAD), 256, 0, stream>>>();
    ln_kernel<<<TSEQ, 256, 0, stream>>>(ln2g + l * DM, ln2b + l * DM);
    // FF1: relu, bf16-split output
    gemm_mfma<128><<<dim3(DFF / 128, TSEQ / 128), 256, 0, stream>>>(
        0, 1, (long)l * DM * DFF, b1 + (long)l * DFF, 0, nullptr, DFF, DM, 1, 1);
    // FF2: residual add into g_h
    gemm_mfma<64><<<dim3(DM / 128, TSEQ / 64), 256, 0, stream>>>(
        1, 2, (long)l * DFF * DM, b2 + (long)l * DM, 0, nullptr, DM, DFF, 0, 3);
  }
  ln_kernel<<<TSEQ, 256, 0, stream>>>(lnfg, lnfb);
  gemm_mfma<128><<<dim3(NVOC / 128, TSEQ / 128), 256, 0, stream>>>(
      0, 3, 0, bvoc, 0, out, NVOC, DM, 0, 0);
}

// Round 2
// 3105.277 us; speedup vs baseline: 4.0708x; 3.1474x over previous
//
#include <hip/hip_runtime.h>

#define TSEQ 2048
#define DM   1024
#define NBLK 4
#define NHEAD 16
#define HDIM 64
#define DFF  4096
#define NVOC 32000

typedef unsigned short u16;
typedef __attribute__((ext_vector_type(8))) short short8;
typedef __attribute__((ext_vector_type(4))) float f32x4;

// ---------------- device-global scratch ----------------
// f32 residual stream
__device__ float g_h[TSEQ * DM];
// bf16 hi/lo split activations (A operands)
__device__ u16 g_xnh[TSEQ * DM];
__device__ u16 g_xnl[TSEQ * DM];
__device__ u16 g_ffh[TSEQ * DFF];
__device__ u16 g_ffl[TSEQ * DFF];
// attention operands, bf16 hi/lo; Q,K row-major [T][D]; V transposed [D][T]
__device__ u16 g_qh[TSEQ * DM], g_ql[TSEQ * DM];
__device__ u16 g_kh[TSEQ * DM], g_kl[TSEQ * DM];
__device__ u16 g_vth[DM * TSEQ], g_vtl[DM * TSEQ];
// bf16 hi/lo split transposed weights, layout [N][K] row-major
__device__ u16 g_wqkvh[NBLK * 3 * DM * DM];
__device__ u16 g_wqkvl[NBLK * 3 * DM * DM];
__device__ u16 g_w1h[NBLK * DM * DFF];
__device__ u16 g_w1l[NBLK * DM * DFF];
__device__ u16 g_w2h[NBLK * DFF * DM];
__device__ u16 g_w2l[NBLK * DFF * DM];
__device__ u16 g_wvh[NVOC * DM];
__device__ u16 g_wvl[NVOC * DM];
__device__ float g_bqkv[NBLK * 3 * DM];

// ---------------- helpers ----------------
__device__ __forceinline__ u16 f2bf(float x) {           // RNE f32 -> bf16
  union { float f; unsigned u; } v; v.f = x;
  unsigned r = (v.u >> 16) & 1u;
  return (u16)((v.u + 0x7fffu + r) >> 16);
}
__device__ __forceinline__ float b2f(u16 h) {
  union { float f; unsigned u; } v; v.u = ((unsigned)h) << 16; return v.f;
}
// async global->LDS, 16B per lane; LDS dest = wave-uniform base + lane*16
__device__ __forceinline__ void load16(const u16* g, u16* l) {
  __builtin_amdgcn_global_load_lds(
      (const __attribute__((address_space(1))) unsigned int*)(const void*)g,
      (__attribute__((address_space(3))) unsigned int*)(void*)l, 16, 0, 0);
}

__device__ __forceinline__ const u16* wsel_h(int s) {
  switch (s) { case 0: return g_wqkvh; case 1: return g_w1h;
               case 2: return g_w2h;   default: return g_wvh; }
}
__device__ __forceinline__ const u16* wsel_l(int s) {
  switch (s) { case 0: return g_wqkvl; case 1: return g_w1l;
               case 2: return g_w2l;   default: return g_wvl; }
}

// ---------------- embedding ----------------
__global__ __launch_bounds__(256) void embed_kernel(const int* __restrict__ x,
                                                    const float* __restrict__ tok,
                                                    const float* __restrict__ pos) {
  int t = blockIdx.x;
  const float* trow = tok + (long)x[t] * DM;
  const float* prow = pos + (long)t * DM;
  float* hrow = g_h + (long)t * DM;
  for (int i = threadIdx.x; i < DM; i += 256)
    hrow[i] = trow[i] + prow[i];
}

// ---------------- layernorm: g_h -> (g_xnh, g_xnl) bf16 split ----------------
__global__ __launch_bounds__(256) void ln_kernel(const float* __restrict__ gamma,
                                                 const float* __restrict__ beta) {
  int t = blockIdx.x;
  const float* xr = g_h + (long)t * DM;
  float s = 0.f, ss = 0.f;
  for (int i = threadIdx.x; i < DM; i += 256) {
    float v = xr[i];
    s += v; ss += v * v;
  }
#pragma unroll
  for (int off = 32; off; off >>= 1) {
    s  += __shfl_down(s, off);
    ss += __shfl_down(ss, off);
  }
  __shared__ float red[2][4];
  int w = threadIdx.x >> 6;
  if ((threadIdx.x & 63) == 0) { red[0][w] = s; red[1][w] = ss; }
  __syncthreads();
  s  = red[0][0] + red[0][1] + red[0][2] + red[0][3];
  ss = red[1][0] + red[1][1] + red[1][2] + red[1][3];
  float mean = s * (1.f / DM);
  float var  = ss * (1.f / DM) - mean * mean;
  float rstd = rsqrtf(var + 1e-5f);
  for (int i = threadIdx.x; i < DM; i += 256) {
    float xv = (xr[i] - mean) * rstd * gamma[i] + beta[i];
    long o = (long)t * DM + i;
    u16 h = f2bf(xv);
    g_xnh[o] = h;
    g_xnl[o] = f2bf(xv - b2f(h));
  }
}

// ---------------- weight transpose + bf16 split ----------------
// src element (k,n) at src[(n>>6)*sH + k*sD + (n&63)]
// dst: [N][K] row-major bf16 hi/lo; grid = (N/64, K/64), 256 threads
__global__ __launch_bounds__(256) void wsplit_t(const float* __restrict__ src,
                                                int dsel, long doff,
                                                int K, long sD, long sH) {
  __shared__ float tile[64][65];
  u16* dh = const_cast<u16*>(wsel_h(dsel)) + doff;
  u16* dl = const_cast<u16*>(wsel_l(dsel)) + doff;
  int n0 = blockIdx.x * 64, k0 = blockIdx.y * 64;
  int tid = threadIdx.x, ln = tid & 63, sub = tid >> 6;
  const float* sbase = src + (long)(n0 >> 6) * sH + ln;
#pragma unroll
  for (int r = 0; r < 16; ++r) {
    int kk = sub * 16 + r;
    tile[kk][ln] = sbase[(long)(k0 + kk) * sD];
  }
  __syncthreads();
#pragma unroll
  for (int r = 0; r < 16; ++r) {
    int nn = sub * 16 + r;
    float v = tile[ln][nn];               // element (k0+ln, n0+nn)
    long o = (long)(n0 + nn) * K + k0 + ln;
    u16 h = f2bf(v);
    dh[o] = h;
    dl[o] = f2bf(v - b2f(h));
  }
}

// concat q/k/v biases per layer into g_bqkv[NBLK][3*DM]
__global__ __launch_bounds__(256) void bias_qkv(const float* __restrict__ bq,
                                                const float* __restrict__ bk,
                                                const float* __restrict__ bv) {
  int i = blockIdx.x * 256 + threadIdx.x;   // grid covers NBLK*3*DM exactly
  int l = i / (3 * DM);
  int j = i % (3 * DM);
  const float* s = (j < DM) ? bq : (j < 2 * DM) ? bk : bv;
  g_bqkv[i] = s[(long)l * DM + (j & (DM - 1))];
}

// ---------------- MFMA GEMM, bf16x3 split precision ----------------
// outmode: 0 = f32 -> Cout; 1 = bf16 split -> g_ffh/g_ffl;
//          2 = qkv: q,k -> bf16 split [T][D]; v -> bf16 split transposed [D][T]
//          3 = residual add -> g_h (f32)
template <int BM>
__global__ __launch_bounds__(256) void gemm_mfma(
    int aSel, int wSel, long woff,
    const float* __restrict__ biasPtr, long boff, float* __restrict__ Cout,
    int N, int K, int relu, int outmode) {
  constexpr int WR = BM / 64;            // wave rows: 2 (BM=128) or 1 (BM=64)
  constexpr int WC = 4 / WR;             // wave cols: 2 or 4
  constexpr int NR = 128 / (16 * WC);    // 16x16 tiles per wave in N: 4 or 2
  __shared__ __align__(16) u16 lA[2][BM * 32];
  __shared__ __align__(16) u16 lB[2][128 * 32];

  const u16* Ah = aSel ? g_ffh : g_xnh;
  const u16* Al = aSel ? g_ffl : g_xnl;
  const u16* Bh = wsel_h(wSel) + woff;
  const u16* Bl = wsel_l(wSel) + woff;
  const float* bias = biasPtr ? biasPtr : (g_bqkv + boff);

  const int tid = threadIdx.x;
  const int w = tid >> 6, lane = tid & 63;
  const int wr = w / WC, wc = w % WC;
  const int n0 = blockIdx.x * 128;
  const int m0 = blockIdx.y * BM;
  const int klane = (lane >> 4) * 8;

  long aoff[WR], boffv[2];
#pragma unroll
  for (int i = 0; i < WR; ++i)
    aoff[i] = (long)(m0 + (i * 4 + w) * 16 + (lane & 15)) * K + klane;
#pragma unroll
  for (int i = 0; i < 2; ++i)
    boffv[i] = (long)(n0 + (i * 4 + w) * 16 + (lane & 15)) * K + klane;

  const u16* pa0 = &lA[0][(wr * 4) * 512 + lane * 8];
  const u16* pa1 = &lA[1][(wr * 4) * 512 + lane * 8];
  const u16* pb0 = &lB[0][(wc * NR) * 512 + lane * 8];
  const u16* pb1 = &lB[1][(wc * NR) * 512 + lane * 8];

  f32x4 acc[4][NR] = {};

  for (int k0 = 0; k0 < K; k0 += 32) {
#pragma unroll
    for (int i = 0; i < WR; ++i) {
      load16(Ah + aoff[i] + k0, &lA[0][(i * 4 + w) * 512]);
      load16(Al + aoff[i] + k0, &lA[1][(i * 4 + w) * 512]);
    }
#pragma unroll
    for (int i = 0; i < 2; ++i) {
      load16(Bh + boffv[i] + k0, &lB[0][(i * 4 + w) * 512]);
      load16(Bl + boffv[i] + k0, &lB[1][(i * 4 + w) * 512]);
    }
    __syncthreads();

    short8 a[4][2], b[NR][2];
#pragma unroll
    for (int mi = 0; mi < 4; ++mi) {
      a[mi][0] = *(const short8*)(const void*)(pa0 + mi * 512);
      a[mi][1] = *(const short8*)(const void*)(pa1 + mi * 512);
    }
#pragma unroll
    for (int ni = 0; ni < NR; ++ni) {
      b[ni][0] = *(const short8*)(const void*)(pb0 + ni * 512);
      b[ni][1] = *(const short8*)(const void*)(pb1 + ni * 512);
    }
#pragma unroll
    for (int mi = 0; mi < 4; ++mi)
#pragma unroll
      for (int ni = 0; ni < NR; ++ni) {
        acc[mi][ni] = __builtin_amdgcn_mfma_f32_16x16x32_bf16(a[mi][0], b[ni][0], acc[mi][ni], 0, 0, 0);
        acc[mi][ni] = __builtin_amdgcn_mfma_f32_16x16x32_bf16(a[mi][0], b[ni][1], acc[mi][ni], 0, 0, 0);
        acc[mi][ni] = __builtin_amdgcn_mfma_f32_16x16x32_bf16(a[mi][1], b[ni][0], acc[mi][ni], 0, 0, 0);
      }
    __syncthreads();
  }

  // epilogue: C/D layout col = lane&15, row = (lane>>4)*4 + r
#pragma unroll
  for (int mi = 0; mi < 4; ++mi)
#pragma unroll
    for (int ni = 0; ni < NR; ++ni) {
      const int col = n0 + wc * (NR * 16) + ni * 16 + (lane & 15);
      const int row0 = m0 + wr * 64 + mi * 16 + ((lane >> 4) << 2);
      const float bv = bias[col];
#pragma unroll
      for (int r = 0; r < 4; ++r) {
        float v2 = acc[mi][ni][r] + bv;
        if (relu) v2 = fmaxf(v2, 0.f);
        const long row = row0 + r;
        if (outmode == 0) {
          Cout[row * (long)N + col] = v2;
        } else if (outmode == 1) {
          long oo = row * (long)N + col;
          u16 hh = f2bf(v2);
          g_ffh[oo] = hh;
          g_ffl[oo] = f2bf(v2 - b2f(hh));
        } else if (outmode == 2) {
          u16 hh = f2bf(v2), ll = f2bf(v2 - b2f(hh));
          if (col < DM) {
            long oo = row * (long)DM + col;
            g_qh[oo] = hh; g_ql[oo] = ll;
          } else if (col < 2 * DM) {
            long oo = row * (long)DM + (col - DM);
            g_kh[oo] = hh; g_kl[oo] = ll;
          } else {
            long oo = (long)(col - 2 * DM) * TSEQ + row;   // V^T [D][T]
            g_vth[oo] = hh; g_vtl[oo] = ll;
          }
        } else {
          long oo = row * (long)N + col;
          g_h[oo] += v2;
        }
      }
    }
}

// ---------------- flash attention, MFMA bf16x3, online softmax ----------------
// Block = (64 q-rows, head), 4 waves; wave w owns q-rows q0+w*16 .. +15.
// K staged frag-order from g_k{h,l} [T][D]; V staged frag-order from V^T [D][T].
// S acc layout: row q = (lane>>4)*4+r, col s = lane&15  ->  softmax reduce =
// shfl_xor(1,2,4,8) over lane&15 + 4-reg max.  P transposed via LDS (stride 72
// u16: 16B-aligned b128 rows, <=2-way write conflicts).  Masked lanes give
// p = exp(-1e30 - m) = 0 -> masking is free in PV.
__global__ __launch_bounds__(256) void attn_kernel() {
  __shared__ __align__(16) u16 kbuf[2][4][2][512];   // [hl][s-tile][kstep][lane*8]
  __shared__ __align__(16) u16 vbuf[2][4][2][512];   // [hl][d-tile][kstep][lane*8]
  __shared__ __align__(16) u16 Ph[64][72];
  __shared__ __align__(16) u16 Pl[64][72];
  const int hd = blockIdx.y;
  const int q0 = blockIdx.x * 64;
  const int tid = threadIdx.x;
  const int w = tid >> 6, lane = tid & 63;
  const int grp = lane >> 4, l16 = lane & 15;
  const float scale = 0.03125f;   // 1/sqrt(DM) = 1/32 (reference scales by D!)

  // Q fragments (hi/lo x 2 k-steps) held in registers for the whole block
  short8 qf[2][2];
#pragma unroll
  for (int hl = 0; hl < 2; ++hl)
#pragma unroll
    for (int ks = 0; ks < 2; ++ks) {
      const u16* src = (hl ? g_ql : g_qh)
          + (long)(q0 + w * 16 + l16) * DM + hd * HDIM + ks * 32 + grp * 8;
      qf[hl][ks] = *(const short8*)(const void*)src;
    }

  float mrun[4] = {-1e30f, -1e30f, -1e30f, -1e30f};
  float lrun[4] = {0.f, 0.f, 0.f, 0.f};
  f32x4 o[4] = {};

  for (int s0 = 0; s0 <= q0; s0 += 64) {
    __syncthreads();                       // prev-iter LDS reads done
    // stage K and V tiles (hi+lo), fragment-ordered: 32 rows, 8 per wave
#pragma unroll
    for (int i = 0; i < 8; ++i) {
      int rid = w * 8 + i;
      int r = rid & 15;
      int hl = r >> 3, nt = (r >> 1) & 3, ks = r & 1;
      if (rid < 16) {
        const u16* src = (hl ? g_kl : g_kh)
            + (long)(s0 + nt * 16 + l16) * DM + hd * HDIM + ks * 32 + grp * 8;
        load16(src, &kbuf[hl][nt][ks][0]);
      } else {
        const u16* src = (hl ? g_vtl : g_vth)
            + (long)(hd * HDIM + nt * 16 + l16) * TSEQ + s0 + ks * 32 + grp * 8;
        load16(src, &vbuf[hl][nt][ks][0]);
      }
    }
    __syncthreads();                       // staging visible (vmcnt drained)

    // S = Q K^T  (bf16x3: hh + hl + lh)
    f32x4 sa[4] = {};
#pragma unroll
    for (int nt = 0; nt < 4; ++nt)
#pragma unroll
      for (int ks = 0; ks < 2; ++ks) {
        short8 kh = *(const short8*)(const void*)&kbuf[0][nt][ks][lane * 8];
        short8 kl = *(const short8*)(const void*)&kbuf[1][nt][ks][lane * 8];
        sa[nt] = __builtin_amdgcn_mfma_f32_16x16x32_bf16(qf[0][ks], kh, sa[nt], 0, 0, 0);
        sa[nt] = __builtin_amdgcn_mfma_f32_16x16x32_bf16(qf[0][ks], kl, sa[nt], 0, 0, 0);
        sa[nt] = __builtin_amdgcn_mfma_f32_16x16x32_bf16(qf[1][ks], kh, sa[nt], 0, 0, 0);
      }

    // scale + causal mask
    float p[4][4];
#pragma unroll
    for (int nt = 0; nt < 4; ++nt)
#pragma unroll
      for (int r = 0; r < 4; ++r) {
        float sc = sa[nt][r] * scale;
        int s = s0 + nt * 16 + l16;
        int q = q0 + w * 16 + grp * 4 + r;
        p[nt][r] = (s > q) ? -1e30f : sc;
      }

    // online softmax, per output row r
#pragma unroll
    for (int r = 0; r < 4; ++r) {
      float rm = fmaxf(fmaxf(p[0][r], p[1][r]), fmaxf(p[2][r], p[3][r]));
#pragma unroll
      for (int off = 8; off; off >>= 1) rm = fmaxf(rm, __shfl_xor(rm, off));
      float mn = fmaxf(mrun[r], rm);
      float al = __expf(mrun[r] - mn);
      mrun[r] = mn;
      float ps = 0.f;
#pragma unroll
      for (int nt = 0; nt < 4; ++nt) { p[nt][r] = __expf(p[nt][r] - mn); ps += p[nt][r]; }
#pragma unroll
      for (int off = 8; off; off >>= 1) ps += __shfl_xor(ps, off);
      lrun[r] = lrun[r] * al + ps;
      o[0][r] *= al; o[1][r] *= al; o[2][r] *= al; o[3][r] *= al;
    }

    // P -> LDS transpose (bf16 hi/lo), wave-private rows -> no barrier needed
#pragma unroll
    for (int nt = 0; nt < 4; ++nt)
#pragma unroll
      for (int r = 0; r < 4; ++r) {
        float pv = p[nt][r];
        u16 hh = f2bf(pv);
        Ph[w * 16 + grp * 4 + r][nt * 16 + l16] = hh;
        Pl[w * 16 + grp * 4 + r][nt * 16 + l16] = f2bf(pv - b2f(hh));
      }

    // O += P V  (bf16x3)
#pragma unroll
    for (int ks = 0; ks < 2; ++ks) {
      short8 pah = *(const short8*)(const void*)&Ph[w * 16 + l16][ks * 32 + grp * 8];
      short8 pal = *(const short8*)(const void*)&Pl[w * 16 + l16][ks * 32 + grp * 8];
#pragma unroll
      for (int nt = 0; nt < 4; ++nt) {
        short8 vh = *(const short8*)(const void*)&vbuf[0][nt][ks][lane * 8];
        short8 vl = *(const short8*)(const void*)&vbuf[1][nt][ks][lane * 8];
        o[nt] = __builtin_amdgcn_mfma_f32_16x16x32_bf16(pah, vh, o[nt], 0, 0, 0);
        o[nt] = __builtin_amdgcn_mfma_f32_16x16x32_bf16(pah, vl, o[nt], 0, 0, 0);
        o[nt] = __builtin_amdgcn_mfma_f32_16x16x32_bf16(pal, vh, o[nt], 0, 0, 0);
      }
    }
  }

  float rl[4];
#pragma unroll
  for (int r = 0; r < 4; ++r) rl[r] = 1.f / lrun[r];
#pragma unroll
  for (int nt = 0; nt < 4; ++nt)
#pragma unroll
    for (int r = 0; r < 4; ++r)
      g_h[(long)(q0 + w * 16 + grp * 4 + r) * DM + hd * HDIM + nt * 16 + l16]
          += o[nt][r] * rl[r];
}

extern "C" void kernel_launch(void* const* d_in, const int* in_sizes, int n_in,
                              void* d_out, int out_size, void* d_ws, size_t ws_size,
                              hipStream_t stream) {
  (void)in_sizes; (void)n_in; (void)out_size; (void)d_ws; (void)ws_size;
  const int*   x    = (const int*)  d_in[0];
  const float* tok  = (const float*)d_in[1];
  const float* pos  = (const float*)d_in[2];
  const float* wq   = (const float*)d_in[3];
  const float* bq   = (const float*)d_in[4];
  const float* wk   = (const float*)d_in[5];
  const float* bk   = (const float*)d_in[6];
  const float* wv   = (const float*)d_in[7];
  const float* bv   = (const float*)d_in[8];
  const float* ln1g = (const float*)d_in[9];
  const float* ln1b = (const float*)d_in[10];
  const float* ln2g = (const float*)d_in[11];
  const float* ln2b = (const float*)d_in[12];
  const float* w1   = (const float*)d_in[13];
  const float* b1   = (const float*)d_in[14];
  const float* w2   = (const float*)d_in[15];
  const float* b2   = (const float*)d_in[16];
  const float* lnfg = (const float*)d_in[17];
  const float* lnfb = (const float*)d_in[18];
  const float* wvoc = (const float*)d_in[19];
  const float* bvoc = (const float*)d_in[20];
  float* out = (float*)d_out;

  // ---- weight conversion (transpose + bf16 hi/lo split), every launch ----
  for (int l = 0; l < NBLK; ++l) {
    long base = (long)l * 3 * DM * DM;
    wsplit_t<<<dim3(DM / 64, DM / 64), 256, 0, stream>>>(
        wq + (long)l * DM * DM, 0, base,                DM, HDIM, (long)DM * HDIM);
    wsplit_t<<<dim3(DM / 64, DM / 64), 256, 0, stream>>>(
        wk + (long)l * DM * DM, 0, base + (long)DM * DM, DM, HDIM, (long)DM * HDIM);
    wsplit_t<<<dim3(DM / 64, DM / 64), 256, 0, stream>>>(
        wv + (long)l * DM * DM, 0, base + 2L * DM * DM, DM, HDIM, (long)DM * HDIM);
    wsplit_t<<<dim3(DFF / 64, DM / 64), 256, 0, stream>>>(
        w1 + (long)l * DM * DFF, 1, (long)l * DM * DFF, DM, DFF, 64);
    wsplit_t<<<dim3(DM / 64, DFF / 64), 256, 0, stream>>>(
        w2 + (long)l * DFF * DM, 2, (long)l * DFF * DM, DFF, DM, 64);
  }
  wsplit_t<<<dim3(NVOC / 64, DM / 64), 256, 0, stream>>>(wvoc, 3, 0, DM, NVOC, 64);
  bias_qkv<<<NBLK * 3 * DM / 256, 256, 0, stream>>>(bq, bk, bv);

  // ---- forward pass ----
  embed_kernel<<<TSEQ, 256, 0, stream>>>(x, tok, pos);
  for (int l = 0; l < NBLK; ++l) {
    long base = (long)l * 3 * DM * DM;
    ln_kernel<<<TSEQ, 256, 0, stream>>>(ln1g + l * DM, ln1b + l * DM);
    // fused QKV: N = 3*DM, writes bf16-split q/k and transposed v
    gemm_mfma<64><<<dim3(3 * DM / 128, TSEQ / 64), 256, 0, stream>>>(
        0, 0, base, nullptr, (long)l * 3 * DM, nullptr, 3 * DM, DM, 0, 2);
    attn_kernel<<<dim3(TSEQ / 64, NHEAD), 256, 0, stream>>>();
    ln_kernel<<<TSEQ, 256, 0, stream>>>(ln2g + l * DM, ln2b + l * DM);
    // FF1: relu, bf16-split output
    gemm_mfma<128><<<dim3(DFF / 128, TSEQ / 128), 256, 0, stream>>>(
        0, 1, (long)l * DM * DFF, b1 + (long)l * DFF, 0, nullptr, DFF, DM, 1, 1);
    // FF2: residual add into g_h
    gemm_mfma<64><<<dim3(DM / 128, TSEQ / 64), 256, 0, stream>>>(
        1, 2, (long)l * DFF * DM, b2 + (long)l * DM, 0, nullptr, DM, DFF, 0, 3);
  }
  ln_kernel<<<TSEQ, 256, 0, stream>>>(lnfg, lnfb);
  gemm_mfma<128><<<dim3(NVOC / 128, TSEQ / 128), 256, 0, stream>>>(
      0, 3, 0, bvoc, 0, out, NVOC, DM, 0, 0);
}